// Round 1
// baseline (147.991 us; speedup 1.0000x reference)
//
#include <hip/hip_runtime.h>
#include <math.h>

// Problem shape (fixed by the reference setup_inputs): B=4, D=32, H=32, W=16
#define NB 4
#define ND 32
#define NH 32
#define NW 16
#define COLS_PER_SAMPLE (ND * NH)        // 1024 columns per sample
#define NCOL (NB * COLS_PER_SAMPLE)      // 4096 columns total
#define NELEM (NCOL * NW)                // 65536 elements per input

// Kernel 1: per (b,d,h) column of 16 w-values, compute min/max occupied w for
// pred mask (logit > 0 <=> sigmoid(logit) > 0.5) and target mask (t > 0.5).
// Coalesced: thread g handles element g; 16-lane subgroup shuffle reduction.
__global__ void hd_col_reduce(const float* __restrict__ logits,
                              const float* __restrict__ targets,
                              int* __restrict__ pwmin, int* __restrict__ pwmax,
                              int* __restrict__ twmin, int* __restrict__ twmax) {
    int g = blockIdx.x * blockDim.x + threadIdx.x;   // 0 .. 65535
    int w = g & (NW - 1);
    int col = g >> 4;
    float lg = logits[g];
    float tg = targets[g];
    bool pm = lg > 0.0f;
    bool tm = tg > 0.5f;
    int pw_min = pm ? w : 1000;
    int pw_max = pm ? w : -1;
    int tw_min = tm ? w : 1000;
    int tw_max = tm ? w : -1;
#pragma unroll
    for (int m = 8; m >= 1; m >>= 1) {
        pw_min = min(pw_min, __shfl_xor(pw_min, m, 16));
        pw_max = max(pw_max, __shfl_xor(pw_max, m, 16));
        tw_min = min(tw_min, __shfl_xor(tw_min, m, 16));
        tw_max = max(tw_max, __shfl_xor(tw_max, m, 16));
    }
    if (w == 0) {
        pwmin[col] = pw_min;
        pwmax[col] = pw_max;
        twmin[col] = tw_min;
        twmax[col] = tw_max;
    }
}

// Kernel 2: one block per sample. Thread i owns pred column i; loop over all
// 1024 target columns (extremes staged in LDS). Integer d^2 arithmetic: the
// max over occupied (pw,tw) pairs within a column pair equals the max over the
// 4 extreme-w combos (convexity in each variable). Block-reduce max; if no
// valid pair exists (either mask empty) the max stays -1 -> inf.
__global__ __launch_bounds__(1024) void hd_pair_max(
    const int* __restrict__ pwmin, const int* __restrict__ pwmax,
    const int* __restrict__ twmin, const int* __restrict__ twmax,
    float* __restrict__ hd) {
    __shared__ int s_twmin[COLS_PER_SAMPLE];
    __shared__ int s_twmax[COLS_PER_SAMPLE];
    __shared__ int s_red[1024 / 64];

    int b = blockIdx.x;
    int tid = threadIdx.x;
    int base = b * COLS_PER_SAMPLE;

    s_twmin[tid] = twmin[base + tid];
    s_twmax[tid] = twmax[base + tid];
    __syncthreads();

    int pmin = pwmin[base + tid];
    int pmax = pwmax[base + tid];
    int pd = tid >> 5;    // column index = d*32 + h
    int ph = tid & 31;

    int best = -1;
    if (pmax >= 0) {
        for (int td = 0; td < ND; ++td) {
            int ddf = pd - td;
            int dd2 = ddf * ddf;
            int rowbase = td * NH;
#pragma unroll 4
            for (int th = 0; th < NH; ++th) {
                int j = rowbase + th;
                int tmax = s_twmax[j];
                if (tmax < 0) continue;          // empty target column
                int tmin = s_twmin[j];
                int dh = ph - th;
                int basew = dd2 + dh * dh;
                int a = pmin - tmin;
                int c = pmin - tmax;
                int d = pmax - tmin;
                int e = pmax - tmax;
                int m = max(max(a * a, c * c), max(d * d, e * e));
                best = max(best, basew + m);
            }
        }
    }

    // wave reduce (64 lanes) then cross-wave via LDS
#pragma unroll
    for (int m = 32; m >= 1; m >>= 1) best = max(best, __shfl_xor(best, m, 64));
    if ((tid & 63) == 0) s_red[tid >> 6] = best;
    __syncthreads();
    if (tid == 0) {
        int mx = s_red[0];
#pragma unroll
        for (int i = 1; i < 1024 / 64; ++i) mx = max(mx, s_red[i]);
        hd[b] = (mx < 0) ? INFINITY : sqrtf((float)mx);
    }
}

// Kernel 3: mean over the B per-sample distances (inf propagates).
__global__ void hd_mean(const float* __restrict__ hd, float* __restrict__ out) {
    float s = 0.0f;
#pragma unroll
    for (int i = 0; i < NB; ++i) s += hd[i];
    out[0] = s * (1.0f / NB);
}

extern "C" void kernel_launch(void* const* d_in, const int* in_sizes, int n_in,
                              void* d_out, int out_size, void* d_ws, size_t ws_size,
                              hipStream_t stream) {
    const float* logits  = (const float*)d_in[0];
    const float* targets = (const float*)d_in[1];
    float* out = (float*)d_out;

    int* ws = (int*)d_ws;
    int* pwmin = ws;
    int* pwmax = ws + NCOL;
    int* twmin = ws + 2 * NCOL;
    int* twmax = ws + 3 * NCOL;
    float* hd  = (float*)(ws + 4 * NCOL);

    hd_col_reduce<<<NELEM / 256, 256, 0, stream>>>(logits, targets,
                                                   pwmin, pwmax, twmin, twmax);
    hd_pair_max<<<NB, 1024, 0, stream>>>(pwmin, pwmax, twmin, twmax, hd);
    hd_mean<<<1, 1, 0, stream>>>(hd, out);
}

// Round 2
// 76.667 us; speedup vs baseline: 1.9303x; 1.9303x over previous
//
#include <hip/hip_runtime.h>
#include <math.h>
#include <limits.h>

// Problem shape (fixed by the reference setup_inputs): B=4, D=32, H=32, W=16
#define NB 4
#define ND 32
#define NH 32
#define NW 16
#define COLS_PER_SAMPLE (ND * NH)        // 1024 columns per sample
#define NCOL (NB * COLS_PER_SAMPLE)      // 4096 columns total
#define NELEM (NCOL * NW)                // 65536 elements per input

// Kernel 1: per (b,d,h) column of 16 w-values, find min/max occupied w for
// pred mask (logit > 0 <=> sigmoid > 0.5) and target mask (t > 0.5).
// One thread per element; a 64-lane wave covers exactly 4 columns, so two
// __ballot()s give all 4 columns' occupancy masks; extremes via ffs/clz.
// Also initializes the per-sample atomic slots and the ticket counter.
__global__ void hd_col_reduce(const float* __restrict__ logits,
                              const float* __restrict__ targets,
                              int2* __restrict__ pext, int2* __restrict__ text,
                              int* __restrict__ smax, int* __restrict__ count) {
    int g = blockIdx.x * blockDim.x + threadIdx.x;   // 0 .. 65535
    float lg = logits[g];
    float tg = targets[g];
    unsigned long long pb = __ballot(lg > 0.0f);
    unsigned long long tb = __ballot(tg > 0.5f);
    int lane = threadIdx.x & 63;
    if ((lane & 15) == 0) {
        int grp = lane >> 4;                         // which of the 4 columns
        int col = g >> 4;
        unsigned pf = (unsigned)((pb >> (grp * 16)) & 0xFFFFull);
        unsigned tf = (unsigned)((tb >> (grp * 16)) & 0xFFFFull);
        int2 pe, te;
        pe.x = pf ? (__ffs(pf) - 1) : 1000;
        pe.y = pf ? (31 - __clz(pf)) : -1;
        te.x = tf ? (__ffs(tf) - 1) : 1000;
        te.y = tf ? (31 - __clz(tf)) : -1;
        pext[col] = pe;
        text[col] = te;
    }
    if (g < NB) smax[g] = -1;
    if (g == NB) *count = 0;
}

// Kernel 2: 1024 blocks x 256 threads. Block -> (sample s, pred-chunk,
// target-chunk); each thread owns one pred column and 16 target columns.
// Max over occupied (pw,tw) within a column pair = max over the 4 extreme-w
// combos (convexity in each variable). Wave-reduce, atomicMax per wave into
// smax[s] (order-independent -> deterministic). Last block (ticket) computes
// sqrt + mean; empty masks leave smax = -1 -> inf, matching the reference.
__global__ __launch_bounds__(256) void hd_pair_max(
    const int2* __restrict__ pext, const int2* __restrict__ text,
    int* __restrict__ smax, int* __restrict__ count,
    float* __restrict__ out) {
    int bid = blockIdx.x;                 // 0..1023
    int s = bid >> 8;                     // 256 blocks per sample
    int pchunk = (bid >> 4) & 15;         // 16 chunks of 64 pred cols
    int tchunk = bid & 15;                // 16 chunks of 64 target cols
    int tid = threadIdx.x;                // 0..255

    int pcol = pchunk * 64 + (tid >> 2);
    int tbase = tchunk * 64 + (tid & 3) * 16;

    int2 pe = pext[s * COLS_PER_SAMPLE + pcol];
    int best = -1;
    if (pe.y >= 0) {
        int pd = pcol >> 5, ph = pcol & 31;
#pragma unroll
        for (int i = 0; i < 16; ++i) {
            int tcol = tbase + i;
            int2 te = text[s * COLS_PER_SAMPLE + tcol];
            if (te.y < 0) continue;       // empty target column
            int td = tcol >> 5, th = tcol & 31;
            int dd = pd - td, dh = ph - th;
            int basew = dd * dd + dh * dh;
            int a = pe.x - te.x, c = pe.x - te.y;
            int d = pe.y - te.x, e = pe.y - te.y;
            int m = max(max(a * a, c * c), max(d * d, e * e));
            best = max(best, basew + m);
        }
    }

#pragma unroll
    for (int m = 32; m >= 1; m >>= 1) best = max(best, __shfl_xor(best, m, 64));
    if ((tid & 63) == 0) atomicMax(&smax[s], best);

    __syncthreads();                      // all 4 waves' atomicMax issued
    if (tid == 0) {
        __threadfence();                  // make this block's maxes visible
        int ticket = atomicAdd(count, 1);
        if (ticket == (int)gridDim.x - 1) {
            float ssum = 0.0f;
#pragma unroll
            for (int i = 0; i < NB; ++i) {
                int m = atomicMax(&smax[i], INT_MIN);   // atomic read
                ssum += (m < 0) ? INFINITY : sqrtf((float)m);
            }
            out[0] = ssum * (1.0f / NB);
        }
    }
}

extern "C" void kernel_launch(void* const* d_in, const int* in_sizes, int n_in,
                              void* d_out, int out_size, void* d_ws, size_t ws_size,
                              hipStream_t stream) {
    const float* logits  = (const float*)d_in[0];
    const float* targets = (const float*)d_in[1];
    float* out = (float*)d_out;

    char* ws = (char*)d_ws;
    int2* pext = (int2*)ws;                          // 4096 * 8 B
    int2* text = (int2*)(ws + NCOL * sizeof(int2));  // 4096 * 8 B
    int*  smax = (int*)(ws + 2 * NCOL * sizeof(int2));
    int*  cnt  = smax + NB;

    hd_col_reduce<<<NELEM / 256, 256, 0, stream>>>(logits, targets,
                                                   pext, text, smax, cnt);
    hd_pair_max<<<1024, 256, 0, stream>>>(pext, text, smax, cnt, out);
}

// Round 3
// 15.623 us; speedup vs baseline: 9.4729x; 4.9074x over previous
//
#include <hip/hip_runtime.h>
#include <math.h>

// Problem shape (fixed by the reference setup_inputs): B=4, D=32, H=32, W=16
#define NB 4
#define ND 32
#define NH 32
#define NW 16
#define COLS_PER_SAMPLE (ND * NH)        // 1024 columns per sample
#define NCOL (NB * COLS_PER_SAMPLE)      // 4096 columns total
#define NELEM (NCOL * NW)                // 65536 elements per input
#define NBLK2 1024                       // pair-max grid (256 blocks/sample)

// Kernel 1: per (b,d,h) column of 16 w-values, find min/max occupied w for
// pred mask (logit > 0 <=> sigmoid > 0.5) and target mask (t > 0.5).
// One thread per element; a 64-lane wave covers exactly 4 columns, so two
// __ballot()s give all 4 columns' occupancy; extremes via ffs/clz.
__global__ void hd_col_reduce(const float* __restrict__ logits,
                              const float* __restrict__ targets,
                              int2* __restrict__ pext, int2* __restrict__ text) {
    int g = blockIdx.x * blockDim.x + threadIdx.x;   // 0 .. 65535
    float lg = logits[g];
    float tg = targets[g];
    unsigned long long pb = __ballot(lg > 0.0f);
    unsigned long long tb = __ballot(tg > 0.5f);
    int lane = threadIdx.x & 63;
    if ((lane & 15) == 0) {
        int grp = lane >> 4;                         // which of the 4 columns
        int col = g >> 4;
        unsigned pf = (unsigned)((pb >> (grp * 16)) & 0xFFFFull);
        unsigned tf = (unsigned)((tb >> (grp * 16)) & 0xFFFFull);
        int2 pe, te;
        pe.x = pf ? (__ffs(pf) - 1) : 1000;
        pe.y = pf ? (31 - __clz(pf)) : -1;
        te.x = tf ? (__ffs(tf) - 1) : 1000;
        te.y = tf ? (31 - __clz(tf)) : -1;
        pext[col] = pe;
        text[col] = te;
    }
}

// Kernel 2: 1024 blocks x 256 threads. Block -> (sample s, pred-chunk,
// target-chunk). Target extremes for the block's 64 target columns staged in
// LDS (one 8B load for tid<64). Each thread: 1 pred column x 16 target
// columns. Max over occupied (pw,tw) within a column pair = max over the 4
// extreme-w combos (convexity in each variable). Plain per-block store of the
// block max — no atomics, no fences (R2's 68us was atomic/threadfence
// serialization, not compute).
__global__ __launch_bounds__(256) void hd_pair_max(
    const int2* __restrict__ pext, const int2* __restrict__ text,
    int* __restrict__ bmax) {
    __shared__ int2 s_te[64];
    __shared__ int s_red[4];

    int bid = blockIdx.x;                 // 0..1023
    int s = bid >> 8;                     // 256 blocks per sample
    int pchunk = (bid >> 4) & 15;         // 16 chunks of 64 pred cols
    int tchunk = bid & 15;                // 16 chunks of 64 target cols
    int tid = threadIdx.x;                // 0..255

    if (tid < 64) s_te[tid] = text[s * COLS_PER_SAMPLE + tchunk * 64 + tid];

    int pcol = pchunk * 64 + (tid >> 2);
    int2 pe = pext[s * COLS_PER_SAMPLE + pcol];
    __syncthreads();

    int best = -1;
    if (pe.y >= 0) {
        int pd = pcol >> 5, ph = pcol & 31;
        int tb0 = (tid & 3) * 16;         // 16 of the block's 64 target cols
#pragma unroll
        for (int i = 0; i < 16; ++i) {
            int tl = tb0 + i;
            int2 te = s_te[tl];
            if (te.y < 0) continue;       // empty target column
            int tcol = tchunk * 64 + tl;
            int td = tcol >> 5, th = tcol & 31;
            int dd = pd - td, dh = ph - th;
            int basew = dd * dd + dh * dh;
            int a = pe.x - te.x, c = pe.x - te.y;
            int d = pe.y - te.x, e = pe.y - te.y;
            int m = max(max(a * a, c * c), max(d * d, e * e));
            best = max(best, basew + m);
        }
    }

#pragma unroll
    for (int m = 32; m >= 1; m >>= 1) best = max(best, __shfl_xor(best, m, 64));
    if ((tid & 63) == 0) s_red[tid >> 6] = best;
    __syncthreads();
    if (tid == 0) {
        int mx = max(max(s_red[0], s_red[1]), max(s_red[2], s_red[3]));
        bmax[bid] = mx;
    }
}

// Kernel 3: one block, 256 threads = 4 waves; wave w reduces sample w's 256
// block-maxes (4 loads/lane), sqrt, then lane-0s combine for the mean.
// Empty masks leave max = -1 -> inf, matching the reference's `valid` logic.
__global__ __launch_bounds__(256) void hd_final(const int* __restrict__ bmax,
                                                float* __restrict__ out) {
    __shared__ float s_val[4];
    int tid = threadIdx.x;
    int w = tid >> 6;                     // sample
    int lane = tid & 63;
    const int* p = bmax + w * 256;
    int m = max(max(p[lane], p[lane + 64]), max(p[lane + 128], p[lane + 192]));
#pragma unroll
    for (int k = 32; k >= 1; k >>= 1) m = max(m, __shfl_xor(m, k, 64));
    if (lane == 0) s_val[w] = (m < 0) ? INFINITY : sqrtf((float)m);
    __syncthreads();
    if (tid == 0) {
        float ssum = s_val[0] + s_val[1] + s_val[2] + s_val[3];
        out[0] = ssum * (1.0f / NB);
    }
}

extern "C" void kernel_launch(void* const* d_in, const int* in_sizes, int n_in,
                              void* d_out, int out_size, void* d_ws, size_t ws_size,
                              hipStream_t stream) {
    const float* logits  = (const float*)d_in[0];
    const float* targets = (const float*)d_in[1];
    float* out = (float*)d_out;

    char* ws = (char*)d_ws;
    int2* pext = (int2*)ws;                          // 4096 * 8 B
    int2* text = (int2*)(ws + NCOL * sizeof(int2));  // 4096 * 8 B
    int*  bmax = (int*)(ws + 2 * NCOL * sizeof(int2)); // 1024 * 4 B

    hd_col_reduce<<<NELEM / 256, 256, 0, stream>>>(logits, targets, pext, text);
    hd_pair_max<<<NBLK2, 256, 0, stream>>>(pext, text, bmax);
    hd_final<<<1, 256, 0, stream>>>(bmax, out);
}

// Round 4
// 11.517 us; speedup vs baseline: 12.8500x; 1.3565x over previous
//
#include <hip/hip_runtime.h>
#include <math.h>

// Problem shape (fixed by the reference setup_inputs): B=4, D=32, H=32, W=16
#define NB 4
#define ND 32
#define NH 32
#define NW 16
#define COLS_PER_SAMPLE (ND * NH)        // 1024 columns per sample
#define VPS (COLS_PER_SAMPLE * NW)       // 16384 voxels per sample
#define NBLK 1024                        // fused grid (256 blocks/sample)

// Fused kernel: block -> (sample s, pred-chunk, target-chunk). Each block
// reads its own 64 pred columns of logits (4 KB) and 64 target columns of
// targets (4 KB) directly — inputs are fully L2-resident, so the 16x column
// re-read across blocks hits L2, and the separate column-reduce kernel (and
// its launch + dependency stall) disappears.
//
// Phase A: per-column min/max occupied w. Thread t loads one float4 (4
// consecutive w's of column t>>2); occupancy scan in registers; combine the
// 4 threads of a column via __shfl_xor(1,2); int2 extremes -> LDS.
// Mask semantics: pred = logit > 0 (<=> sigmoid > 0.5), target = t > 0.5.
//
// Phase B: pair max. Max over occupied (pw,tw) within a column pair equals
// the max over the 4 extreme-w combos (convexity in each variable). Each
// thread: 1 pred column x 16 target columns, integer arithmetic.
//
// Phase C: block max -> bmax[bid] (plain store; atomics/fences cost 68 us in
// R2, so the cross-block combine stays in a second tiny kernel).
__global__ __launch_bounds__(256) void hd_fused(
    const float* __restrict__ logits, const float* __restrict__ targets,
    int* __restrict__ bmax) {
    __shared__ int2 s_pe[64];
    __shared__ int2 s_te[64];
    __shared__ int s_red[4];

    int bid = blockIdx.x;                 // 0..1023
    int s = bid >> 8;                     // 256 blocks per sample
    int pchunk = (bid >> 4) & 15;         // 16 chunks of 64 pred cols
    int tchunk = bid & 15;                // 16 chunks of 64 target cols
    int tid = threadIdx.x;                // 0..255

    // ---- Phase A: column extremes ----
    const float4* pl = (const float4*)(logits  + s * VPS + pchunk * 1024);
    const float4* tl = (const float4*)(targets + s * VPS + tchunk * 1024);
    float4 pv = pl[tid];
    float4 tv = tl[tid];
    int q = (tid & 3) * 4;                // w-offset of this quarter-column

    int pmn = 1000, pmx = -1;
    if (pv.x > 0.0f) { pmn = q;              pmx = q;     }
    if (pv.y > 0.0f) { pmn = min(pmn, q + 1); pmx = q + 1; }
    if (pv.z > 0.0f) { pmn = min(pmn, q + 2); pmx = q + 2; }
    if (pv.w > 0.0f) { pmn = min(pmn, q + 3); pmx = q + 3; }
    int tmn = 1000, tmx = -1;
    if (tv.x > 0.5f) { tmn = q;              tmx = q;     }
    if (tv.y > 0.5f) { tmn = min(tmn, q + 1); tmx = q + 1; }
    if (tv.z > 0.5f) { tmn = min(tmn, q + 2); tmx = q + 2; }
    if (tv.w > 0.5f) { tmn = min(tmn, q + 3); tmx = q + 3; }

#pragma unroll
    for (int m = 1; m <= 2; m <<= 1) {
        pmn = min(pmn, __shfl_xor(pmn, m, 64));
        pmx = max(pmx, __shfl_xor(pmx, m, 64));
        tmn = min(tmn, __shfl_xor(tmn, m, 64));
        tmx = max(tmx, __shfl_xor(tmx, m, 64));
    }
    if ((tid & 3) == 0) {
        s_pe[tid >> 2] = make_int2(pmn, pmx);
        s_te[tid >> 2] = make_int2(tmn, tmx);
    }
    __syncthreads();

    // ---- Phase B: pair max ----
    int pl_idx = tid >> 2;                // local pred column 0..63
    int2 pe = s_pe[pl_idx];
    int best = -1;
    if (pe.y >= 0) {
        int pcol = pchunk * 64 + pl_idx;
        int pd = pcol >> 5, ph = pcol & 31;
        int tb0 = (tid & 3) * 16;         // 16 of the block's 64 target cols
#pragma unroll
        for (int i = 0; i < 16; ++i) {
            int tl_idx = tb0 + i;
            int2 te = s_te[tl_idx];
            if (te.y < 0) continue;       // empty target column
            int tcol = tchunk * 64 + tl_idx;
            int td = tcol >> 5, th = tcol & 31;
            int dd = pd - td, dh = ph - th;
            int basew = dd * dd + dh * dh;
            int a = pe.x - te.x, c = pe.x - te.y;
            int d = pe.y - te.x, e = pe.y - te.y;
            int m = max(max(a * a, c * c), max(d * d, e * e));
            best = max(best, basew + m);
        }
    }

    // ---- Phase C: block reduce, plain store ----
#pragma unroll
    for (int m = 32; m >= 1; m >>= 1) best = max(best, __shfl_xor(best, m, 64));
    if ((tid & 63) == 0) s_red[tid >> 6] = best;
    __syncthreads();
    if (tid == 0)
        bmax[bid] = max(max(s_red[0], s_red[1]), max(s_red[2], s_red[3]));
}

// Final kernel: one block, 256 threads = 4 waves; wave w reduces sample w's
// 256 block-maxes, sqrt, lane-0s combine for the mean. Empty masks leave
// max = -1 -> inf, matching the reference's `valid` logic.
__global__ __launch_bounds__(256) void hd_final(const int* __restrict__ bmax,
                                                float* __restrict__ out) {
    __shared__ float s_val[4];
    int tid = threadIdx.x;
    int w = tid >> 6;                     // sample
    int lane = tid & 63;
    const int* p = bmax + w * 256;
    int m = max(max(p[lane], p[lane + 64]), max(p[lane + 128], p[lane + 192]));
#pragma unroll
    for (int k = 32; k >= 1; k >>= 1) m = max(m, __shfl_xor(m, k, 64));
    if (lane == 0) s_val[w] = (m < 0) ? INFINITY : sqrtf((float)m);
    __syncthreads();
    if (tid == 0) {
        float ssum = s_val[0] + s_val[1] + s_val[2] + s_val[3];
        out[0] = ssum * (1.0f / NB);
    }
}

extern "C" void kernel_launch(void* const* d_in, const int* in_sizes, int n_in,
                              void* d_out, int out_size, void* d_ws, size_t ws_size,
                              hipStream_t stream) {
    const float* logits  = (const float*)d_in[0];
    const float* targets = (const float*)d_in[1];
    float* out = (float*)d_out;
    int* bmax = (int*)d_ws;               // NBLK * 4 B

    hd_fused<<<NBLK, 256, 0, stream>>>(logits, targets, bmax);
    hd_final<<<1, 256, 0, stream>>>(bmax, out);
}